// Round 7
// baseline (157.697 us; speedup 1.0000x reference)
//
#include <hip/hip_runtime.h>

// N=4096 nodes, D=512 d_model, H=4 heads.
//
// Math reduction: softmax row-score is constant along the softmax axis so it
// cancels; exp(-1e10)==0 and self-loops give deg>=1, so attn = adj/deg,
// head-independent. A_self/A_neigh/LeakyReLU are dead. Additionally (R11),
// rownorm(adj) rows sum to 1, so matmul re-associates:
//   out = relu( rownorm(adj) @ (nodes @ Mmat + 1*bias2^T) )
//       = relu( (rownorm(adj) @ nodes) @ Mmat + bias2 )
//   Mmat = W_node @ Kbar,  bias2 = b_node @ Kbar,  Kbar = mean_h K[h].
// -> aggregate FIRST (fp32 nodes, cache-resident gather), then ONE GEMM.
// Pipeline shrinks 3 stages -> 2; the gather hides under the adj scan.
//  k1 (4168 blocks, 512thr): bid<64 Mmat GEMM (k-split) || bid<72 bias2 ||
//     else per-row scan->list(LDS)->gather fp32 nodes->mean->aggBf (bf16).
//  k2 (512 blocks, 512thr): out = relu(aggBf @ Mmat + bias2), fp32 out.
// Harness floor (2-3x 268MB ws-poison fills ~41us each + small memsets) is
// ~105-110us of the total and not controllable.

typedef short  short8 __attribute__((ext_vector_type(8)));
typedef float  f32x4  __attribute__((ext_vector_type(4)));

__device__ inline unsigned short f2bf(float f) {
    union { float f; unsigned int u; } v; v.f = f;
    unsigned int u = v.u;
    u += 0x7fffu + ((u >> 16) & 1u);       // round-nearest-even
    return (unsigned short)(u >> 16);
}

__device__ inline void gl_lds16(const void* gp, void* lp) {
    // async global->LDS, 16B/lane; lds base wave-uniform, HW writes base+lane*16.
    __builtin_amdgcn_global_load_lds(
        (const __attribute__((address_space(1))) void*)gp,
        (__attribute__((address_space(3))) void*)lp, 16, 0, 0);
}

// ---------------------------------------------------------------- k1: prep
// bid <  64     : MmatT[f][d] = bf16(sum_k Kbar[k][f]*W[d][k]), k-split waves
// bid in [64,72): bias2[f] = b @ Kbar
// bid >= 72     : row r=bid-72: scan adj row -> lst (LDS) -> gather fp32
//                 nodes rows -> fp32 mean -> aggBf[r][:] (bf16)
__global__ __launch_bounds__(512, 4) void prep_kernel(
        const float* __restrict__ nodes, const float* __restrict__ adj,
        const float* __restrict__ W, const float* __restrict__ b,
        const float* __restrict__ K,
        unsigned short* __restrict__ MmatT, float* __restrict__ bias2,
        unsigned short* __restrict__ aggBf,
        int N, int D, int H) {
    __shared__ union {
        struct {
            unsigned short As[2][64][40];   // [half][f][k] +8 pad (2-way free)
            unsigned short Bs[2][64][40];   // [half][d][k]
        } g;
        float red64[64][64];                // cross-half fp32 reduce (aliases)
        int   lst[1024];
    } sm;
    __shared__ float red2[8][64];
    __shared__ int cnt;

    const int bid = blockIdx.x;
    const int tid = threadIdx.x;
    const int DD  = D * D;
    const int lane = tid & 63, wave = tid >> 6;
    const int l15 = lane & 15, quad = lane >> 4;

    if (bid < 64) {
        // 64x64 tile; 8 waves = 2x2 output grid x 2 k-halves.
        const int by = bid >> 3, bx = bid & 7;
        const int f0 = by * 64, d0 = bx * 64;
        const float invH = 1.0f / (float)H;
        const int h  = tid >> 8;            // k-half 0/1
        const int th = tid & 255;
        const int wy = (wave >> 1) & 1, wx = wave & 1;
        const int kk = th >> 3;             // 0..31 (k within step)
        const int ff = (th & 7) * 8;        // 0..56 (f within tile)
        const int dr = th >> 2;             // 0..63 (d row for W staging)
        const int dk = (th & 3) * 8;
        const int kh = h * 256;             // this half's k base

        f32x4 acc[2][2] = {};
        for (int k0 = 0; k0 < 256; k0 += 32) {
            f32x4 kv[4][2];
#pragma unroll
            for (int hh = 0; hh < 4; ++hh) {
                const float* kp = K + ((size_t)hh * D + (kh + k0 + kk)) * D + f0 + ff;
                kv[hh][0] = *reinterpret_cast<const f32x4*>(kp);
                kv[hh][1] = *reinterpret_cast<const f32x4*>(kp + 4);
            }
            const float* wp = W + (size_t)(d0 + dr) * D + kh + k0 + dk;
            f32x4 wu = *reinterpret_cast<const f32x4*>(wp);
            f32x4 wv = *reinterpret_cast<const f32x4*>(wp + 4);

            float s[8];
#pragma unroll
            for (int j = 0; j < 4; ++j) {
                s[j]     = kv[0][0][j] + kv[1][0][j] + kv[2][0][j] + kv[3][0][j];
                s[j + 4] = kv[0][1][j] + kv[1][1][j] + kv[2][1][j] + kv[3][1][j];
            }
            short8 bv;
#pragma unroll
            for (int j = 0; j < 4; ++j) {
                bv[j]     = (short)f2bf(wu[j]);
                bv[j + 4] = (short)f2bf(wv[j]);
            }
            __syncthreads();               // prev iter's frag reads done
#pragma unroll
            for (int j = 0; j < 8; ++j)    // transposed scalar stores
                sm.g.As[h][ff + j][kk] = f2bf(s[j] * invH);
            *reinterpret_cast<short8*>(&sm.g.Bs[h][dr][dk]) = bv;
            __syncthreads();
            short8 a0 = *reinterpret_cast<const short8*>(&sm.g.As[h][wy * 32 +      l15][quad * 8]);
            short8 a1 = *reinterpret_cast<const short8*>(&sm.g.As[h][wy * 32 + 16 + l15][quad * 8]);
            short8 b0 = *reinterpret_cast<const short8*>(&sm.g.Bs[h][wx * 32 +      l15][quad * 8]);
            short8 b1 = *reinterpret_cast<const short8*>(&sm.g.Bs[h][wx * 32 + 16 + l15][quad * 8]);
            acc[0][0] = __builtin_amdgcn_mfma_f32_16x16x32_bf16(a0, b0, acc[0][0], 0, 0, 0);
            acc[0][1] = __builtin_amdgcn_mfma_f32_16x16x32_bf16(a0, b1, acc[0][1], 0, 0, 0);
            acc[1][0] = __builtin_amdgcn_mfma_f32_16x16x32_bf16(a1, b0, acc[1][0], 0, 0, 0);
            acc[1][1] = __builtin_amdgcn_mfma_f32_16x16x32_bf16(a1, b1, acc[1][1], 0, 0, 0);
        }
        __syncthreads();                   // all frag reads done; As/Bs reusable
        // cross-half reduce: half1 parks fp32 partials in LDS, half0 adds and
        // writes bf16. Deterministic order.
        // C/D layout: col = lane&15, row = (lane>>4)*4 + reg  [m89-verified]
        if (h == 1) {
#pragma unroll
            for (int mi = 0; mi < 2; ++mi)
#pragma unroll
                for (int ni = 0; ni < 2; ++ni)
#pragma unroll
                    for (int r = 0; r < 4; ++r)
                        sm.red64[wy * 32 + mi * 16 + quad * 4 + r]
                                [wx * 32 + ni * 16 + l15] = acc[mi][ni][r];
        }
        __syncthreads();
        if (h == 0) {
#pragma unroll
            for (int mi = 0; mi < 2; ++mi)
#pragma unroll
                for (int ni = 0; ni < 2; ++ni) {
                    int col = d0 + wx * 32 + ni * 16 + l15;
#pragma unroll
                    for (int r = 0; r < 4; ++r) {
                        int row = f0 + wy * 32 + mi * 16 + quad * 4 + r;
                        float v = acc[mi][ni][r] +
                            sm.red64[wy * 32 + mi * 16 + quad * 4 + r]
                                    [wx * 32 + ni * 16 + l15];
                        MmatT[(size_t)row * D + col] = f2bf(v);
                    }
                }
        }
    } else if (bid < 72) {
        // bias2[f] = (1/H)*sum_d b[d]*sum_h K[h][d][f]; 8 blocks x 64 f.
        const int f0 = (bid - 64) * 64;
        const int fl = tid & 63, grp = tid >> 6;
        const float invH = 1.0f / (float)H;
        float a = 0.f;
        for (int d0i = grp * 64; d0i < grp * 64 + 64; d0i += 4) {
            float v[4] = {0.f, 0.f, 0.f, 0.f};
#pragma unroll
            for (int dd = 0; dd < 4; ++dd)
#pragma unroll
                for (int hh = 0; hh < 4; ++hh)
                    v[dd] += K[((size_t)hh * D + d0i + dd) * D + f0 + fl];
#pragma unroll
            for (int dd = 0; dd < 4; ++dd) a += b[d0i + dd] * v[dd];
        }
        red2[grp][fl] = a;
        __syncthreads();
        if (tid < 64) {
            float s = 0.f;
#pragma unroll
            for (int gg = 0; gg < 8; ++gg) s += red2[gg][tid];
            bias2[f0 + tid] = s * invH;
        }
    } else {
        // scan + gather-aggregate for one row (assumes N==4096, D==512).
        const int row = bid - 72;
        if (tid == 0) cnt = 0;
        __syncthreads();
        const f32x4* ap = reinterpret_cast<const f32x4*>(adj + (size_t)row * N + tid * 8);
        f32x4 av[2];
        av[0] = ap[0];
        av[1] = ap[1];
#pragma unroll
        for (int c = 0; c < 2; ++c) {
            int b4 = tid * 8 + c * 4;
#pragma unroll
            for (int j = 0; j < 4; ++j)
                if (av[c][j] > 0.5f) {
                    int p = atomicAdd(&cnt, 1);
                    if (p < 1024) sm.lst[p] = b4 + j;
                }
        }
        __syncthreads();
        int deg = cnt; if (deg > 1024) deg = 1024;

        // gather fp32 nodes rows: col = tid (4B x 512 thr = 2KB/row, coalesced)
        float acc = 0.f;
        int k = 0;
        for (; k + 8 <= deg; k += 8) {
            float u[8];
#pragma unroll
            for (int j = 0; j < 8; ++j)
                u[j] = nodes[(size_t)sm.lst[k + j] * D + tid];
#pragma unroll
            for (int j = 0; j < 8; ++j) acc += u[j];
        }
        for (; k < deg; ++k)
            acc += nodes[(size_t)sm.lst[k] * D + tid];

        float inv = 1.f / (float)deg;      // deg>=1 (self-loop)
        aggBf[(size_t)row * D + tid] = f2bf(acc * inv);
    }
}

// ----------------------------------------------------------- k2: out GEMM
// out[n][f] = relu( sum_d aggBf[n][d]*MmatT[f][d] + bias2[f] ), fp32 out.
// 64x64 tile, BK=32, 512 threads / 8 waves (2 row x 4 col; each wave 32x16
// out, acc[2]). Waves 0-3 stage A, 4-7 stage B: one global_load_lds w16 per
// thread per buffer, dbuf with counted vmcnt(1), raw s_barrier. LDS linear
// (global_load_lds requirement); both-sides XOR involution (rule #21):
// source colgroup ^ ((row>>1)&3), same XOR on fragment reads. XCD remap.
__global__ __launch_bounds__(512) void outgemm_kernel(
        const unsigned short* __restrict__ aggBf,
        const unsigned short* __restrict__ MmatT,
        const float* __restrict__ bias2, float* __restrict__ out, int D) {
    __shared__ unsigned short As[2][64][32];
    __shared__ unsigned short Bs[2][64][32];
    const int bid = blockIdx.x;
    // XCD-chunked remap (512 = 8 XCDs x 64): each XCD gets 8 consecutive
    // by-panels -> A-panel (0.5MB) + B (0.5MB) L2-resident per XCD.
    const int lb = (bid & 7) * 64 + (bid >> 3);
    const int by = lb >> 3, bx = lb & 7;
    const int tid = threadIdx.x;
    const int lane = tid & 63, wave = tid >> 6;    // 0..7
    const int wy = wave >> 2, wx = wave & 3;       // 2 x 4 wave grid
    const int l15 = lane & 15, quad = lane >> 4;

    // staging: tid<256 -> A granule st=tid; tid>=256 -> B granule st=tid-256.
    // granule st = (row st>>2, colgroup st&3); content pre-swizzled:
    // phys (r,pg) holds logical (r, pg ^ s(r)), s(r)=(r>>1)&3.
    const int st  = tid & 255;
    const int cgl = ((st & 3) ^ ((st >> 3) & 3)) * 8;
    const unsigned short* Gp = (tid < 256)
        ? aggBf + (size_t)(by * 64 + (st >> 2)) * D + cgl
        : MmatT + (size_t)(bx * 64 + (st >> 2)) * D + cgl;
    unsigned short* S0 = (tid < 256)
        ? (&As[0][0][0] + wave * 512)              // wave-uniform + lane*16B
        : (&Bs[0][0][0] + (wave - 4) * 512);
    unsigned short* S1 = (tid < 256)
        ? (&As[1][0][0] + wave * 512)
        : (&Bs[1][0][0] + (wave - 4) * 512);

    const int ra = wy * 32 + l15;                  // A rows (and ra+16)
    const int rb = wx * 16 + l15;                  // B row
    const int qa = (quad ^ ((ra >> 1) & 3)) * 8;   // s(r+16)==s(r)
    const int qb = (quad ^ ((rb >> 1) & 3)) * 8;

    f32x4 acc[2] = {};
    gl_lds16(Gp, S0);

    int cur = 0;
#pragma unroll
    for (int k0 = 0; k0 < 512; k0 += 32) {
        if (k0 + 32 < 512) {
            gl_lds16(Gp + k0 + 32, cur ? S0 : S1);
            asm volatile("s_waitcnt vmcnt(1)" ::: "memory");   // cur tile landed
        } else {
            asm volatile("s_waitcnt vmcnt(0)" ::: "memory");
        }
        __builtin_amdgcn_s_barrier();          // all waves' segments present
        __builtin_amdgcn_sched_barrier(0);     // no LDS reads hoisted above
        const unsigned short* Af = cur ? &As[1][0][0] : &As[0][0][0];
        const unsigned short* Bf = cur ? &Bs[1][0][0] : &Bs[0][0][0];
        short8 a0 = *reinterpret_cast<const short8*>(Af + (ra     ) * 32 + qa);
        short8 a1 = *reinterpret_cast<const short8*>(Af + (ra + 16) * 32 + qa);
        short8 b0 = *reinterpret_cast<const short8*>(Bf + (rb     ) * 32 + qb);
        acc[0] = __builtin_amdgcn_mfma_f32_16x16x32_bf16(a0, b0, acc[0], 0, 0, 0);
        acc[1] = __builtin_amdgcn_mfma_f32_16x16x32_bf16(a1, b0, acc[1], 0, 0, 0);
        __builtin_amdgcn_sched_barrier(0);     // no LDS reads sunk below
        asm volatile("s_waitcnt lgkmcnt(0)" ::: "memory");
        __builtin_amdgcn_s_barrier();          // reads done before buffer reuse
        cur ^= 1;
    }

    // C/D layout: col = lane&15, row = (lane>>4)*4 + reg  [m89-verified]
    {
        const int col = bx * 64 + wx * 16 + l15;
        const float bvl = bias2[col];
#pragma unroll
        for (int mi = 0; mi < 2; ++mi)
#pragma unroll
            for (int r = 0; r < 4; ++r) {
                int row = by * 64 + wy * 32 + mi * 16 + quad * 4 + r;
                float v = acc[mi][r] + bvl;
                out[(size_t)row * D + col] = v > 0.f ? v : 0.f;
            }
    }
}

extern "C" void kernel_launch(void* const* d_in, const int* in_sizes, int n_in,
                              void* d_out, int out_size, void* d_ws, size_t ws_size,
                              hipStream_t stream) {
    const float* nodes  = (const float*)d_in[0];
    const float* adj    = (const float*)d_in[1];
    const float* W_node = (const float*)d_in[2];
    const float* b_node = (const float*)d_in[3];
    const float* K      = (const float*)d_in[4];
    // d_in[5] A_self, d_in[6] A_neigh: dead (softmax row-constant cancels).

    const int D  = in_sizes[3];              // 512
    const int N  = in_sizes[0] / D;          // 4096
    const int H  = in_sizes[4] / (D * D);    // 4
    const int DD = D * D;

    float* out = (float*)d_out;

    // ws layout (bytes): MmatT[DD*2] | bias2[D*4] | aggBf[N*D*2]
    char* ws = (char*)d_ws;
    unsigned short* MmatT = (unsigned short*)(ws);
    size_t off = (size_t)DD * 2;
    float*          bias2 = (float*)(ws + off);          off += (size_t)D * 4;
    unsigned short* aggBf = (unsigned short*)(ws + off);

    prep_kernel<<<dim3(64 + 8 + N), 512, 0, stream>>>(
        nodes, adj, W_node, b_node, K, MmatT, bias2, aggBf, N, D, H);

    outgemm_kernel<<<dim3((N / 64) * (D / 64)), 512, 0, stream>>>(
        aggBf, MmatT, bias2, out, D);
}

// Round 8
// 145.552 us; speedup vs baseline: 1.0834x; 1.0834x over previous
//
#include <hip/hip_runtime.h>

// N=4096 nodes, D=512 d_model, H=4 heads.
//
// Math reduction (unchanged): softmax row-score is constant along the softmax
// axis so it cancels; exp(-1e10)==0 and self-loops give deg>=1, so
// attn = adj/deg, head-independent. A_self/A_neigh/LeakyReLU are dead.
//   out = relu( rownorm(adj) @ (nodes @ Mmat + bias2) ),
//   Mmat = W_node @ Kbar,  bias2 = b_node @ Kbar,  Kbar = mean_h K[h].
//
// R12: REVERT to R10 (measured best, 146.6us). R11's re-association (gather
// fp32 nodes before the GEMM) regressed: FETCH 162MB -> fp32 gather (2x bytes,
// 8MB array > 4MB XCD L2) missed L2 and serialized inside the scan kernel.
// Lesson pair: (R9) the 64MB adj scan must start at t=0; (R11) the gather must
// hit a <=4MB bf16 array. R10 satisfies both:
//  k1 prep (4680 blocks, 512thr): adj scan -> neighbor lists (t=0, long pole)
//     || Mmat GEMM (k-split) || bias2 || nodes->bf16 cast.
//  k2 gemm2 (512 blocks, 512thr, 8 waves): g = nodesBf @ Mmat + bias2 (bf16).
//  k3 aggregate (4096 blocks): out = relu(mean of gathered g rows), g 4MB
//     L2-resident.
// Harness floor (2-3x 268MB ws-poison fills ~41us each + small memsets) is
// ~105-110us of the total and not controllable. Controllable ~36us vs ~26us
// floor; all structural alternatives measured worse (R5/R9/R11).

typedef short  short8 __attribute__((ext_vector_type(8)));
typedef float  f32x4  __attribute__((ext_vector_type(4)));

__device__ inline unsigned short f2bf(float f) {
    union { float f; unsigned int u; } v; v.f = f;
    unsigned int u = v.u;
    u += 0x7fffu + ((u >> 16) & 1u);       // round-nearest-even
    return (unsigned short)(u >> 16);
}

__device__ inline void gl_lds16(const void* gp, void* lp) {
    // async global->LDS, 16B/lane; lds base wave-uniform, HW writes base+lane*16.
    __builtin_amdgcn_global_load_lds(
        (const __attribute__((address_space(1))) void*)gp,
        (__attribute__((address_space(3))) void*)lp, 16, 0, 0);
}

// ---------------------------------------------------------------- k1: prep
// bid <  64          : MmatT[f][d] = bf16(sum_k Kbar[k][f]*W[d][k]), k-split
// bid in [64,72)     : bias2[f] = b @ Kbar
// bid in [72,72+N)   : neighbor-list build for row bid-72
// bid >= 72+N        : nodes -> bf16 cast (grid-strided)
__global__ __launch_bounds__(512, 4) void prep_kernel(
        const float* __restrict__ nodes, const float* __restrict__ adj,
        const float* __restrict__ W, const float* __restrict__ b,
        const float* __restrict__ K,
        unsigned short* __restrict__ MmatT, float* __restrict__ bias2,
        unsigned short* __restrict__ nodesBf,
        int* __restrict__ degArr, int* __restrict__ nbrArr,
        int N, int D, int H, int numCast) {
    __shared__ union {
        struct {
            unsigned short As[2][64][40];   // [half][f][k] +8 pad (2-way free)
            unsigned short Bs[2][64][40];   // [half][d][k]
        } g;
        float red64[64][64];                // cross-half fp32 reduce (aliases)
        int   lst[1024];
    } sm;
    __shared__ float red2[8][64];
    __shared__ int cnt;

    const int bid = blockIdx.x;
    const int tid = threadIdx.x;
    const int DD  = D * D;
    const int lane = tid & 63, wave = tid >> 6;
    const int l15 = lane & 15, quad = lane >> 4;

    if (bid < 64) {
        // 64x64 tile; 8 waves = 2x2 output grid x 2 k-halves.
        const int by = bid >> 3, bx = bid & 7;
        const int f0 = by * 64, d0 = bx * 64;
        const float invH = 1.0f / (float)H;
        const int h  = tid >> 8;            // k-half 0/1
        const int th = tid & 255;
        const int wy = (wave >> 1) & 1, wx = wave & 1;
        const int kk = th >> 3;             // 0..31 (k within step)
        const int ff = (th & 7) * 8;        // 0..56 (f within tile)
        const int dr = th >> 2;             // 0..63 (d row for W staging)
        const int dk = (th & 3) * 8;
        const int kh = h * 256;             // this half's k base

        f32x4 acc[2][2] = {};
        for (int k0 = 0; k0 < 256; k0 += 32) {
            f32x4 kv[4][2];
#pragma unroll
            for (int hh = 0; hh < 4; ++hh) {
                const float* kp = K + ((size_t)hh * D + (kh + k0 + kk)) * D + f0 + ff;
                kv[hh][0] = *reinterpret_cast<const f32x4*>(kp);
                kv[hh][1] = *reinterpret_cast<const f32x4*>(kp + 4);
            }
            const float* wp = W + (size_t)(d0 + dr) * D + kh + k0 + dk;
            f32x4 wu = *reinterpret_cast<const f32x4*>(wp);
            f32x4 wv = *reinterpret_cast<const f32x4*>(wp + 4);

            float s[8];
#pragma unroll
            for (int j = 0; j < 4; ++j) {
                s[j]     = kv[0][0][j] + kv[1][0][j] + kv[2][0][j] + kv[3][0][j];
                s[j + 4] = kv[0][1][j] + kv[1][1][j] + kv[2][1][j] + kv[3][1][j];
            }
            short8 bv;
#pragma unroll
            for (int j = 0; j < 4; ++j) {
                bv[j]     = (short)f2bf(wu[j]);
                bv[j + 4] = (short)f2bf(wv[j]);
            }
            __syncthreads();               // prev iter's frag reads done
#pragma unroll
            for (int j = 0; j < 8; ++j)    // transposed scalar stores
                sm.g.As[h][ff + j][kk] = f2bf(s[j] * invH);
            *reinterpret_cast<short8*>(&sm.g.Bs[h][dr][dk]) = bv;
            __syncthreads();
            short8 a0 = *reinterpret_cast<const short8*>(&sm.g.As[h][wy * 32 +      l15][quad * 8]);
            short8 a1 = *reinterpret_cast<const short8*>(&sm.g.As[h][wy * 32 + 16 + l15][quad * 8]);
            short8 b0 = *reinterpret_cast<const short8*>(&sm.g.Bs[h][wx * 32 +      l15][quad * 8]);
            short8 b1 = *reinterpret_cast<const short8*>(&sm.g.Bs[h][wx * 32 + 16 + l15][quad * 8]);
            acc[0][0] = __builtin_amdgcn_mfma_f32_16x16x32_bf16(a0, b0, acc[0][0], 0, 0, 0);
            acc[0][1] = __builtin_amdgcn_mfma_f32_16x16x32_bf16(a0, b1, acc[0][1], 0, 0, 0);
            acc[1][0] = __builtin_amdgcn_mfma_f32_16x16x32_bf16(a1, b0, acc[1][0], 0, 0, 0);
            acc[1][1] = __builtin_amdgcn_mfma_f32_16x16x32_bf16(a1, b1, acc[1][1], 0, 0, 0);
        }
        __syncthreads();                   // all frag reads done; As/Bs reusable
        // cross-half reduce: half1 parks fp32 partials in LDS, half0 adds and
        // writes bf16. Deterministic order.
        // C/D layout: col = lane&15, row = (lane>>4)*4 + reg  [m89-verified]
        if (h == 1) {
#pragma unroll
            for (int mi = 0; mi < 2; ++mi)
#pragma unroll
                for (int ni = 0; ni < 2; ++ni)
#pragma unroll
                    for (int r = 0; r < 4; ++r)
                        sm.red64[wy * 32 + mi * 16 + quad * 4 + r]
                                [wx * 32 + ni * 16 + l15] = acc[mi][ni][r];
        }
        __syncthreads();
        if (h == 0) {
#pragma unroll
            for (int mi = 0; mi < 2; ++mi)
#pragma unroll
                for (int ni = 0; ni < 2; ++ni) {
                    int col = d0 + wx * 32 + ni * 16 + l15;
#pragma unroll
                    for (int r = 0; r < 4; ++r) {
                        int row = f0 + wy * 32 + mi * 16 + quad * 4 + r;
                        float v = acc[mi][ni][r] +
                            sm.red64[wy * 32 + mi * 16 + quad * 4 + r]
                                    [wx * 32 + ni * 16 + l15];
                        MmatT[(size_t)row * D + col] = f2bf(v);
                    }
                }
        }
    } else if (bid < 72) {
        // bias2[f] = (1/H)*sum_d b[d]*sum_h K[h][d][f]; 8 blocks x 64 f.
        const int f0 = (bid - 64) * 64;
        const int fl = tid & 63, grp = tid >> 6;
        const float invH = 1.0f / (float)H;
        float a = 0.f;
        for (int d0i = grp * 64; d0i < grp * 64 + 64; d0i += 4) {
            float v[4] = {0.f, 0.f, 0.f, 0.f};
#pragma unroll
            for (int dd = 0; dd < 4; ++dd)
#pragma unroll
                for (int hh = 0; hh < 4; ++hh)
                    v[dd] += K[((size_t)hh * D + d0i + dd) * D + f0 + fl];
#pragma unroll
            for (int dd = 0; dd < 4; ++dd) a += b[d0i + dd] * v[dd];
        }
        red2[grp][fl] = a;
        __syncthreads();
        if (tid < 64) {
            float s = 0.f;
#pragma unroll
            for (int gg = 0; gg < 8; ++gg) s += red2[gg][tid];
            bias2[f0 + tid] = s * invH;
        }
    } else if (bid < 72 + N) {
        // neighbor-list build for one adj row (assumes N==4096, 512 thr).
        const int row = bid - 72;
        if (tid == 0) cnt = 0;
        __syncthreads();
        const f32x4* ap = reinterpret_cast<const f32x4*>(adj + (size_t)row * N + tid * 8);
        f32x4 av[2];
        av[0] = ap[0];
        av[1] = ap[1];
#pragma unroll
        for (int c = 0; c < 2; ++c) {
            int b4 = tid * 8 + c * 4;
#pragma unroll
            for (int j = 0; j < 4; ++j)
                if (av[c][j] > 0.5f) {
                    int p = atomicAdd(&cnt, 1);
                    if (p < 1024) sm.lst[p] = b4 + j;
                }
        }
        __syncthreads();
        int deg = cnt; if (deg > 1024) deg = 1024;
        if (tid == 0) degArr[row] = deg;
        for (int i = tid; i < deg; i += 512)
            nbrArr[(size_t)row * 1024 + i] = sm.lst[i];
    } else {
        // nodes -> bf16 cast, grid-strided over remaining blocks.
        const int total  = (N * D) >> 3;          // 8-elt granules
        const int stride = numCast << 9;          // *512 threads
        for (int i = (bid - 72 - N) * 512 + tid; i < total; i += stride) {
            const float* p = nodes + (size_t)i * 8;
            f32x4 x = *reinterpret_cast<const f32x4*>(p);
            f32x4 y = *reinterpret_cast<const f32x4*>(p + 4);
            short8 o;
#pragma unroll
            for (int j = 0; j < 4; ++j) {
                o[j]     = (short)f2bf(x[j]);
                o[j + 4] = (short)f2bf(y[j]);
            }
            *reinterpret_cast<short8*>(nodesBf + (size_t)i * 8) = o;
        }
    }
}

// ------------------------------------------------------------- k2: gemm2
// g[n][f] = bf16( sum_d nodesBf[n][d]*MmatT[f][d] + bias2[f] )
// 64x64 tile, BK=32, 512 threads / 8 waves (2 row x 4 col; each wave 32x16
// out, acc[2]). Waves 0-3 stage A, 4-7 stage B: one global_load_lds w16 per
// thread per buffer, dbuf with counted vmcnt(1), raw s_barrier. LDS linear
// (global_load_lds requirement); both-sides XOR involution (rule #21):
// source colgroup ^ ((row>>1)&3), same XOR on fragment reads. XCD remap.
__global__ __launch_bounds__(512) void gemm2_kernel(
        const unsigned short* __restrict__ nodesBf,
        const unsigned short* __restrict__ MmatT,
        const float* __restrict__ bias2, unsigned short* __restrict__ g, int D) {
    __shared__ unsigned short As[2][64][32];
    __shared__ unsigned short Bs[2][64][32];
    const int bid = blockIdx.x;
    // XCD-chunked remap (512 = 8 XCDs x 64): each XCD gets 8 consecutive
    // by-panels -> A-panel (0.5MB) + B (0.5MB) L2-resident per XCD.
    const int lb = (bid & 7) * 64 + (bid >> 3);
    const int by = lb >> 3, bx = lb & 7;
    const int tid = threadIdx.x;
    const int lane = tid & 63, wave = tid >> 6;    // 0..7
    const int wy = wave >> 2, wx = wave & 3;       // 2 x 4 wave grid
    const int l15 = lane & 15, quad = lane >> 4;

    // staging: tid<256 -> A granule st=tid; tid>=256 -> B granule st=tid-256.
    // granule st = (row st>>2, colgroup st&3); content pre-swizzled:
    // phys (r,pg) holds logical (r, pg ^ s(r)), s(r)=(r>>1)&3.
    const int st  = tid & 255;
    const int cgl = ((st & 3) ^ ((st >> 3) & 3)) * 8;
    const unsigned short* Gp = (tid < 256)
        ? nodesBf + (size_t)(by * 64 + (st >> 2)) * D + cgl
        : MmatT   + (size_t)(bx * 64 + (st >> 2)) * D + cgl;
    unsigned short* S0 = (tid < 256)
        ? (&As[0][0][0] + wave * 512)              // wave-uniform + lane*16B
        : (&Bs[0][0][0] + (wave - 4) * 512);
    unsigned short* S1 = (tid < 256)
        ? (&As[1][0][0] + wave * 512)
        : (&Bs[1][0][0] + (wave - 4) * 512);

    const int ra = wy * 32 + l15;                  // A rows (and ra+16)
    const int rb = wx * 16 + l15;                  // B row
    const int qa = (quad ^ ((ra >> 1) & 3)) * 8;   // s(r+16)==s(r)
    const int qb = (quad ^ ((rb >> 1) & 3)) * 8;

    f32x4 acc[2] = {};
    gl_lds16(Gp, S0);

    int cur = 0;
#pragma unroll
    for (int k0 = 0; k0 < 512; k0 += 32) {
        if (k0 + 32 < 512) {
            gl_lds16(Gp + k0 + 32, cur ? S0 : S1);
            asm volatile("s_waitcnt vmcnt(1)" ::: "memory");   // cur tile landed
        } else {
            asm volatile("s_waitcnt vmcnt(0)" ::: "memory");
        }
        __builtin_amdgcn_s_barrier();          // all waves' segments present
        __builtin_amdgcn_sched_barrier(0);     // no LDS reads hoisted above
        const unsigned short* Af = cur ? &As[1][0][0] : &As[0][0][0];
        const unsigned short* Bf = cur ? &Bs[1][0][0] : &Bs[0][0][0];
        short8 a0 = *reinterpret_cast<const short8*>(Af + (ra     ) * 32 + qa);
        short8 a1 = *reinterpret_cast<const short8*>(Af + (ra + 16) * 32 + qa);
        short8 b0 = *reinterpret_cast<const short8*>(Bf + (rb     ) * 32 + qb);
        acc[0] = __builtin_amdgcn_mfma_f32_16x16x32_bf16(a0, b0, acc[0], 0, 0, 0);
        acc[1] = __builtin_amdgcn_mfma_f32_16x16x32_bf16(a1, b0, acc[1], 0, 0, 0);
        __builtin_amdgcn_sched_barrier(0);     // no LDS reads sunk below
        asm volatile("s_waitcnt lgkmcnt(0)" ::: "memory");
        __builtin_amdgcn_s_barrier();          // reads done before buffer reuse
        cur ^= 1;
    }

    // C/D layout: col = lane&15, row = (lane>>4)*4 + reg  [m89-verified]
    {
        const int col = bx * 64 + wx * 16 + l15;
        const float bvl = bias2[col];
#pragma unroll
        for (int mi = 0; mi < 2; ++mi)
#pragma unroll
            for (int r = 0; r < 4; ++r) {
                int row = by * 64 + wy * 32 + mi * 16 + quad * 4 + r;
                g[(size_t)row * D + col] = f2bf(acc[mi][r] + bvl);
            }
    }
}

// --------------------------------------------------------- k3: aggregate
// out[i,:] = relu( (1/deg_i) * sum_{j in nbr(i)} g[j,:] ), lists precomputed.
__global__ __launch_bounds__(256) void aggregate_kernel(
        const int* __restrict__ degArr, const int* __restrict__ nbrArr,
        const unsigned short* __restrict__ g, float* __restrict__ out,
        int N, int D) {
    const int row = blockIdx.x;
    const int tid = threadIdx.x;
    __shared__ int lst[1024];
    const int deg = degArr[row];
    for (int i = tid; i < deg; i += 256) lst[i] = nbrArr[(size_t)row * 1024 + i];
    __syncthreads();

    const int col = tid * 2;
    float acc0 = 0.f, acc1 = 0.f;
    int k = 0;
    for (; k + 8 <= deg; k += 8) {
        unsigned int u[8];
#pragma unroll
        for (int j = 0; j < 8; ++j)
            u[j] = *reinterpret_cast<const unsigned int*>(&g[(size_t)lst[k + j] * D + col]);
#pragma unroll
        for (int j = 0; j < 8; ++j) {
            union { unsigned int i; float f; } lo, hi;
            lo.i = u[j] << 16; hi.i = u[j] & 0xffff0000u;
            acc0 += lo.f; acc1 += hi.f;
        }
    }
    for (; k < deg; ++k) {
        unsigned int u = *reinterpret_cast<const unsigned int*>(&g[(size_t)lst[k] * D + col]);
        union { unsigned int i; float f; } lo, hi;
        lo.i = u << 16; hi.i = u & 0xffff0000u;
        acc0 += lo.f; acc1 += hi.f;
    }

    float inv = deg > 0 ? 1.f / (float)deg : 0.f;
    acc0 *= inv; acc1 *= inv;
    float2 o;
    o.x = acc0 > 0.f ? acc0 : 0.f;
    o.y = acc1 > 0.f ? acc1 : 0.f;
    *reinterpret_cast<float2*>(&out[(size_t)row * D + col]) = o;
}

extern "C" void kernel_launch(void* const* d_in, const int* in_sizes, int n_in,
                              void* d_out, int out_size, void* d_ws, size_t ws_size,
                              hipStream_t stream) {
    const float* nodes  = (const float*)d_in[0];
    const float* adj    = (const float*)d_in[1];
    const float* W_node = (const float*)d_in[2];
    const float* b_node = (const float*)d_in[3];
    const float* K      = (const float*)d_in[4];
    // d_in[5] A_self, d_in[6] A_neigh: dead (softmax row-constant cancels).

    const int D  = in_sizes[3];              // 512
    const int N  = in_sizes[0] / D;          // 4096
    const int H  = in_sizes[4] / (D * D);    // 4
    const int DD = D * D;

    float* out = (float*)d_out;

    // ws layout (bytes):
    //   MmatT[DD*2] | bias2[D*4] | nodesBf[N*D*2] | g[N*D*2] | deg[N*4] | nbr[N*1024*4]
    char* ws = (char*)d_ws;
    unsigned short* MmatT   = (unsigned short*)(ws);
    size_t off = (size_t)DD * 2;
    float*          bias2   = (float*)(ws + off);          off += (size_t)D * 4;
    unsigned short* nodesBf = (unsigned short*)(ws + off); off += (size_t)N * D * 2;
    unsigned short* g_bf16  = (unsigned short*)(ws + off); off += (size_t)N * D * 2;
    int*            degArr  = (int*)(ws + off);            off += (size_t)N * 4;
    int*            nbrArr  = (int*)(ws + off);

    const int numCast = 512;
    prep_kernel<<<dim3(64 + 8 + N + numCast), 512, 0, stream>>>(
        nodes, adj, W_node, b_node, K, MmatT, bias2, nodesBf, degArr, nbrArr,
        N, D, H, numCast);

    gemm2_kernel<<<dim3((N / 64) * (D / 64)), 512, 0, stream>>>(
        nodesBf, MmatT, bias2, g_bf16, D);

    aggregate_kernel<<<dim3(N), 256, 0, stream>>>(degArr, nbrArr, g_bf16, out, N, D);
}